// Round 1
// baseline (323.539 us; speedup 1.0000x reference)
//
#include <hip/hip_runtime.h>
#include <math.h>

#ifndef M_PI
#define M_PI 3.14159265358979323846
#endif

#define T 2048
#define EDGE 256
#define TT 1536            // trimmed timesteps
#define PHA_N 50
#define AMP_N 30
#define NBANDS 80
#define NBINS 18
#define NBC 16             // B*C = 2*8
#define FMAX 768           // forward DFT bins stored [0, FMAX); max needed bin = 634

// Compute the inclusive frequency-bin range [fl, fh] for a band, replicating
// the reference's float32 band edges vs exact quarter-Hz freq grid.
__device__ __forceinline__ void band_range(int band, int* fl, int* fh) {
    double lo, hi;
    if (band < PHA_N) {
        double mid = 2.0 + (double)band * (18.0 / 49.0);   // linspace(2,20,50)
        lo = (double)(float)(mid * 0.75);
        hi = (double)(float)(mid * 1.25);
    } else {
        int j = band - PHA_N;
        double mid = 60.0 + (double)j * (81.0 / 29.0);     // linspace(60,141,30)
        lo = (double)(float)(mid * 0.875);
        hi = (double)(float)(mid * 1.125);
    }
    int l = (int)ceil(lo * 4.0);     // freq = 0.25*f ; f >= 4*lo
    int h = (int)floor(hi * 4.0);    // f <= 4*hi
    if (l < 1) l = 1;
    if (h > FMAX - 1) h = FMAX - 1;
    *fl = l; *fh = h;
}

// Kernel A: forward DFT. X[bc][f] = sum_t x[t] e^{-2pi i f t / T}, f in [0,768)
__global__ void dft_kernel(const float* __restrict__ x, double* __restrict__ Xf) {
    __shared__ float xs[T];
    __shared__ double twc[T];
    __shared__ double tws[T];
    const int bc = blockIdx.x;
    const int tid = threadIdx.x;
    for (int i = tid; i < T; i += blockDim.x) {
        xs[i] = x[bc * T + i];
        double a = (2.0 * M_PI / (double)T) * (double)i;
        double s, c;
        sincos(a, &s, &c);
        twc[i] = c; tws[i] = s;
    }
    __syncthreads();
    const int f = blockIdx.y * blockDim.x + tid;
    if (f >= FMAX) return;
    double re = 0.0, im = 0.0;
    int m = 0;
    for (int t = 0; t < T; ++t) {
        double v = (double)xs[t];
        re += v * twc[m];
        im -= v * tws[m];
        m = (m + f) & (T - 1);
    }
    Xf[(size_t)(bc * FMAX + f) * 2 + 0] = re;
    Xf[(size_t)(bc * FMAX + f) * 2 + 1] = im;
}

// Kernel B: per (bc, band), synthesize analytic signal on trimmed window,
// emit phase-bin index (bands < 50) or amplitude (bands >= 50).
__global__ void band_kernel(const double* __restrict__ Xf,
                            unsigned char* __restrict__ idx_buf,
                            float* __restrict__ amp_buf) {
    __shared__ double twc[T];
    __shared__ double tws[T];
    __shared__ double bre[160];
    __shared__ double bim[160];
    const int bc = blockIdx.x;
    const int band = blockIdx.y;
    const int tid = threadIdx.x;
    int fl, fh;
    band_range(band, &fl, &fh);
    const int nb = fh - fl + 1;
    for (int i = tid; i < T; i += blockDim.x) {
        double a = (2.0 * M_PI / (double)T) * (double)i;
        double s, c;
        sincos(a, &s, &c);
        twc[i] = c; tws[i] = s;
    }
    for (int i = tid; i < nb; i += blockDim.x) {
        bre[i] = Xf[(size_t)(bc * FMAX + fl + i) * 2 + 0];
        bim[i] = Xf[(size_t)(bc * FMAX + fl + i) * 2 + 1];
    }
    __syncthreads();
    for (int trel = tid; trel < TT; trel += blockDim.x) {
        const int t = trel + EDGE;
        const int step = t & (T - 1);
        int m = (fl * t) & (T - 1);
        double re = 0.0, im = 0.0;
        for (int i = 0; i < nb; ++i) {
            double c = twc[m], s = tws[m];
            double xr = bre[i], xi = bim[i];
            re += xr * c - xi * s;
            im += xr * s + xi * c;
            m = (m + step) & (T - 1);
        }
        if (band < PHA_N) {
            double pha = atan2(im, re);                  // (-pi, pi]
            double width = 2.0 * M_PI / (double)NBINS;
            int b = (int)floor((pha + M_PI) / width);
            if (b < 0) b = 0;
            if (b > NBINS - 1) b = NBINS - 1;
            idx_buf[(size_t)(bc * PHA_N + band) * TT + trel] = (unsigned char)b;
        } else {
            double amp = sqrt(re * re + im * im) * (2.0 / (double)T);
            amp_buf[(size_t)(bc * AMP_N + (band - PHA_N)) * TT + trel] = (float)amp;
        }
    }
}

// Kernel C: per (bc, phase band p): histogram counts, per-amp-band bin sums, MI.
#define PK 19   // padded bin stride for partials
__global__ void mi_kernel(const unsigned char* __restrict__ idx_buf,
                          const float* __restrict__ amp_buf,
                          float* __restrict__ out) {
    __shared__ unsigned char sidx[TT];
    __shared__ int counts[NBINS];
    __shared__ double part[240 * PK];       // (a*8+g)*PK + k
    __shared__ double sums[AMP_N * NBINS];
    const int blk = blockIdx.x;             // bc*50 + p
    const int bc = blk / PHA_N;
    const int p = blk % PHA_N;
    const int tid = threadIdx.x;

    for (int i = tid; i < TT; i += blockDim.x)
        sidx[i] = idx_buf[(size_t)(bc * PHA_N + p) * TT + i];
    if (tid < NBINS) counts[tid] = 0;
    for (int i = tid; i < 240 * PK; i += blockDim.x) part[i] = 0.0;
    __syncthreads();

    for (int i = tid; i < TT; i += blockDim.x)
        atomicAdd(&counts[sidx[i]], 1);

    if (tid < 240) {
        const int a = tid >> 3;     // 0..29
        const int g = tid & 7;      // 0..7
        const float* ap = amp_buf + (size_t)(bc * AMP_N + a) * TT;
        double* myp = part + tid * PK;
        for (int t = g; t < TT; t += 8) {
            int k = sidx[t];
            myp[k] += (double)ap[t];
        }
    }
    __syncthreads();

    for (int i = tid; i < AMP_N * NBINS; i += blockDim.x) {
        int a = i / NBINS, k = i - a * NBINS;
        double s = 0.0;
        for (int g = 0; g < 8; ++g) s += part[(a * 8 + g) * PK + k];
        sums[i] = s;
    }
    __syncthreads();

    if (tid < AMP_N) {
        const int a = tid;
        double m[NBINS], tot = 0.0;
        for (int k = 0; k < NBINS; ++k) {
            double cnt = (double)counts[k];
            double denom = cnt > 1e-9 ? cnt : 1e-9;
            m[k] = sums[a * NBINS + k] / denom;
            tot += m[k];
        }
        double dt = tot > 1e-9 ? tot : 1e-9;
        double acc = 0.0;
        for (int k = 0; k < NBINS; ++k) {
            double pr = m[k] / dt;
            acc += pr * log(pr + 1e-9);
        }
        const double lognb = log((double)NBINS);
        double mi = (lognb + acc) / lognb;
        out[(size_t)(bc * PHA_N + p) * AMP_N + a] = (float)mi;
    }
}

extern "C" void kernel_launch(void* const* d_in, const int* in_sizes, int n_in,
                              void* d_out, int out_size, void* d_ws, size_t ws_size,
                              hipStream_t stream) {
    const float* x = (const float*)d_in[0];
    float* out = (float*)d_out;
    char* ws = (char*)d_ws;
    // workspace layout (all written before read; 0xAA poison is overwritten):
    //   Xf:      16*768 complex double = 196608 B
    //   idx_buf: 16*50*1536 u8        = 1228800 B
    //   amp_buf: 16*30*1536 f32       = 2949120 B   (total ~4.4 MB)
    double* Xf = (double*)ws;
    unsigned char* idx_buf = (unsigned char*)(ws + 196608);
    float* amp_buf = (float*)(ws + 196608 + 1228800);

    dft_kernel<<<dim3(NBC, FMAX / 256), 256, 0, stream>>>(x, Xf);
    band_kernel<<<dim3(NBC, NBANDS), 256, 0, stream>>>(Xf, idx_buf, amp_buf);
    mi_kernel<<<NBC * PHA_N, 256, 0, stream>>>(idx_buf, amp_buf, out);
}

// Round 2
// 182.252 us; speedup vs baseline: 1.7752x; 1.7752x over previous
//
#include <hip/hip_runtime.h>
#include <math.h>

#ifndef M_PI
#define M_PI 3.14159265358979323846
#endif

#define T 2048
#define EDGE 256
#define TT 1536            // trimmed timesteps
#define PHA_N 50
#define AMP_N 30
#define NBANDS 80
#define NBINS 18
#define NBC 16             // B*C = 2*8
#define FMAX 768           // forward DFT bins stored [0, FMAX); max needed bin = 634
#define NCH 8              // t-chunks for forward DFT
#define CHLEN (T / NCH)    // 256

// Inclusive frequency-bin range [fl, fh] for a band, replicating the
// reference's float32 band edges vs exact quarter-Hz freq grid.
__device__ __forceinline__ void band_range(int band, int* fl, int* fh) {
    double lo, hi;
    if (band < PHA_N) {
        double mid = 2.0 + (double)band * (18.0 / 49.0);   // linspace(2,20,50)
        lo = (double)(float)(mid * 0.75);
        hi = (double)(float)(mid * 1.25);
    } else {
        int j = band - PHA_N;
        double mid = 60.0 + (double)j * (81.0 / 29.0);     // linspace(60,141,30)
        lo = (double)(float)(mid * 0.875);
        hi = (double)(float)(mid * 1.125);
    }
    int l = (int)ceil(lo * 4.0);     // freq = 0.25*f ; f >= 4*lo
    int h = (int)floor(hi * 4.0);    // f <= 4*hi
    if (l < 1) l = 1;
    if (h > FMAX - 1) h = FMAX - 1;
    *fl = l; *fh = h;
}

// Kernel A: chunked forward DFT partials via complex oscillator recurrence.
// Xp[((bc*FMAX + f)*NCH + ch)*2 + {re,im}] = sum_{t in chunk} x[t] e^{-i 2pi f t/T}
__global__ void dft_kernel(const float* __restrict__ x, double* __restrict__ Xp) {
    __shared__ float xs[CHLEN];
    const int bc = blockIdx.x;
    const int fb = blockIdx.y;
    const int ch = blockIdx.z;
    const int tid = threadIdx.x;
    const int t0 = ch * CHLEN;
    if (tid < CHLEN) xs[tid] = x[bc * T + t0 + tid];
    __syncthreads();
    const int f = fb * 256 + tid;
    // oscillator: cur = e^{-i 2pi f t / T}, step w = e^{-i 2pi f / T}
    const double om = 2.0 * M_PI / (double)T;
    double s0, c0, sw, cw;
    sincos(om * (double)((f * t0) & (T - 1)), &s0, &c0);
    sincos(om * (double)(f & (T - 1)), &sw, &cw);
    double curR = c0, curI = -s0;          // e^{-i th0}
    const double wR = cw, wI = -sw;        // e^{-i om f}
    double accR = 0.0, accI = 0.0;
    #pragma unroll 4
    for (int t = 0; t < CHLEN; ++t) {
        double v = (double)xs[t];
        accR += v * curR;
        accI += v * curI;
        double nR = curR * wR - curI * wI;
        double nI = curR * wI + curI * wR;
        curR = nR; curI = nI;
    }
    Xp[(size_t)((bc * FMAX + f) * NCH + ch) * 2 + 0] = accR;
    Xp[(size_t)((bc * FMAX + f) * NCH + ch) * 2 + 1] = accI;
}

// Kernel B: per (bc, band) analytic-signal synthesis via oscillator recurrence
// over band bins. Each thread carries its 6 t-values through one bin pass.
__global__ void band_kernel(const double* __restrict__ Xp,
                            unsigned char* __restrict__ idx_buf,
                            float* __restrict__ amp_buf) {
    __shared__ double sXr[160];
    __shared__ double sXi[160];
    const int bc = blockIdx.x;
    const int band = blockIdx.y;
    const int tid = threadIdx.x;
    int fl, fh;
    band_range(band, &fl, &fh);
    const int nb = fh - fl + 1;
    // stage band bins, reducing the NCH chunk partials
    for (int i = tid; i < nb; i += 256) {
        const double* p = Xp + (size_t)((bc * FMAX + fl + i) * NCH) * 2;
        double r = 0.0, im = 0.0;
        #pragma unroll
        for (int c = 0; c < NCH; ++c) { r += p[2 * c]; im += p[2 * c + 1]; }
        sXr[i] = r; sXi[i] = im;
    }
    __syncthreads();

    const double om = 2.0 * M_PI / (double)T;
    double curR[6], curI[6], wR[6], wI[6], accR[6], accI[6];
    #pragma unroll
    for (int j = 0; j < 6; ++j) {
        const int t = tid + j * 256 + EDGE;
        double s, c;
        sincos(om * (double)((fl * t) & (T - 1)), &s, &c);
        curR[j] = c; curI[j] = s;          // e^{+i om fl t}
        sincos(om * (double)(t & (T - 1)), &s, &c);
        wR[j] = c; wI[j] = s;              // e^{+i om t}
        accR[j] = 0.0; accI[j] = 0.0;
    }
    for (int i = 0; i < nb; ++i) {
        const double Xr = sXr[i], Xi = sXi[i];   // broadcast read
        #pragma unroll
        for (int j = 0; j < 6; ++j) {
            accR[j] += Xr * curR[j] - Xi * curI[j];
            accI[j] += Xr * curI[j] + Xi * curR[j];
            double nR = curR[j] * wR[j] - curI[j] * wI[j];
            double nI = curR[j] * wI[j] + curI[j] * wR[j];
            curR[j] = nR; curI[j] = nI;
        }
    }
    #pragma unroll
    for (int j = 0; j < 6; ++j) {
        const int trel = tid + j * 256;
        if (band < PHA_N) {
            double pha = atan2(accI[j], accR[j]);        // (-pi, pi]
            double width = 2.0 * M_PI / (double)NBINS;
            int b = (int)floor((pha + M_PI) / width);
            if (b < 0) b = 0;
            if (b > NBINS - 1) b = NBINS - 1;
            idx_buf[(size_t)(bc * PHA_N + band) * TT + trel] = (unsigned char)b;
        } else {
            double amp = sqrt(accR[j] * accR[j] + accI[j] * accI[j]) * (2.0 / (double)T);
            amp_buf[(size_t)(bc * AMP_N + (band - PHA_N)) * TT + trel] = (float)amp;
        }
    }
}

// Kernel C: per (bc, phase band p): histogram counts, per-amp-band bin sums, MI.
#define PK 19   // padded bin stride for partials
__global__ void mi_kernel(const unsigned char* __restrict__ idx_buf,
                          const float* __restrict__ amp_buf,
                          float* __restrict__ out) {
    __shared__ unsigned char sidx[TT];
    __shared__ int counts[NBINS];
    __shared__ double part[240 * PK];       // (a*8+g)*PK + k
    __shared__ double sums[AMP_N * NBINS];
    const int blk = blockIdx.x;             // bc*50 + p
    const int bc = blk / PHA_N;
    const int p = blk % PHA_N;
    const int tid = threadIdx.x;

    for (int i = tid; i < TT; i += blockDim.x)
        sidx[i] = idx_buf[(size_t)(bc * PHA_N + p) * TT + i];
    if (tid < NBINS) counts[tid] = 0;
    for (int i = tid; i < 240 * PK; i += blockDim.x) part[i] = 0.0;
    __syncthreads();

    for (int i = tid; i < TT; i += blockDim.x)
        atomicAdd(&counts[sidx[i]], 1);

    if (tid < 240) {
        const int a = tid >> 3;     // 0..29
        const int g = tid & 7;      // 0..7
        const float* ap = amp_buf + (size_t)(bc * AMP_N + a) * TT;
        double* myp = part + tid * PK;
        for (int t = g; t < TT; t += 8) {
            int k = sidx[t];
            myp[k] += (double)ap[t];
        }
    }
    __syncthreads();

    for (int i = tid; i < AMP_N * NBINS; i += blockDim.x) {
        int a = i / NBINS, k = i - a * NBINS;
        double s = 0.0;
        for (int g = 0; g < 8; ++g) s += part[(a * 8 + g) * PK + k];
        sums[i] = s;
    }
    __syncthreads();

    if (tid < AMP_N) {
        const int a = tid;
        double m[NBINS], tot = 0.0;
        for (int k = 0; k < NBINS; ++k) {
            double cnt = (double)counts[k];
            double denom = cnt > 1e-9 ? cnt : 1e-9;
            m[k] = sums[a * NBINS + k] / denom;
            tot += m[k];
        }
        double dt = tot > 1e-9 ? tot : 1e-9;
        double acc = 0.0;
        for (int k = 0; k < NBINS; ++k) {
            double pr = m[k] / dt;
            acc += pr * log(pr + 1e-9);
        }
        const double lognb = log((double)NBINS);
        double mi = (lognb + acc) / lognb;
        out[(size_t)(bc * PHA_N + p) * AMP_N + a] = (float)mi;
    }
}

extern "C" void kernel_launch(void* const* d_in, const int* in_sizes, int n_in,
                              void* d_out, int out_size, void* d_ws, size_t ws_size,
                              hipStream_t stream) {
    const float* x = (const float*)d_in[0];
    float* out = (float*)d_out;
    char* ws = (char*)d_ws;
    // workspace layout (all regions fully written before read each call):
    //   idx_buf: 16*50*1536 u8                    = 1,228,800 B
    //   amp_buf: 16*30*1536 f32                   = 2,949,120 B
    //   Xp:      16*768*8 chunks complex double   = 1,572,864 B   (~5.5 MB total)
    unsigned char* idx_buf = (unsigned char*)ws;
    float* amp_buf = (float*)(ws + 1228800);
    double* Xp = (double*)(ws + 1228800 + 2949120);

    dft_kernel<<<dim3(NBC, FMAX / 256, NCH), 256, 0, stream>>>(x, Xp);
    band_kernel<<<dim3(NBC, NBANDS), 256, 0, stream>>>(Xp, idx_buf, amp_buf);
    mi_kernel<<<NBC * PHA_N, 256, 0, stream>>>(idx_buf, amp_buf, out);
}

// Round 3
// 162.164 us; speedup vs baseline: 1.9951x; 1.1239x over previous
//
#include <hip/hip_runtime.h>
#include <math.h>

#ifndef M_PI
#define M_PI 3.14159265358979323846
#endif

#define T 2048
#define EDGE 256
#define TT 1536            // trimmed timesteps
#define PHA_N 50
#define AMP_N 30
#define NBANDS 80
#define NBINS 18
#define NBC 16             // B*C = 2*8
#define FMAX 768           // forward DFT bins stored [0, FMAX); max needed bin = 634
#define NCH 8              // t-chunks for forward DFT
#define CHLEN (T / NCH)    // 256

// Inclusive frequency-bin range [fl, fh] for a band, replicating the
// reference's float32 band edges vs exact quarter-Hz freq grid.
__device__ __forceinline__ void band_range(int band, int* fl, int* fh) {
    double lo, hi;
    if (band < PHA_N) {
        double mid = 2.0 + (double)band * (18.0 / 49.0);   // linspace(2,20,50)
        lo = (double)(float)(mid * 0.75);
        hi = (double)(float)(mid * 1.25);
    } else {
        int j = band - PHA_N;
        double mid = 60.0 + (double)j * (81.0 / 29.0);     // linspace(60,141,30)
        lo = (double)(float)(mid * 0.875);
        hi = (double)(float)(mid * 1.125);
    }
    int l = (int)ceil(lo * 4.0);     // freq = 0.25*f ; f >= 4*lo
    int h = (int)floor(hi * 4.0);    // f <= 4*hi
    if (l < 1) l = 1;
    if (h > FMAX - 1) h = FMAX - 1;
    *fl = l; *fh = h;
}

// Kernel A: chunked forward DFT partials via complex oscillator recurrence.
__global__ void dft_kernel(const float* __restrict__ x, double* __restrict__ Xp) {
    __shared__ float xs[CHLEN];
    const int bc = blockIdx.x;
    const int fb = blockIdx.y;
    const int ch = blockIdx.z;
    const int tid = threadIdx.x;
    const int t0 = ch * CHLEN;
    if (tid < CHLEN) xs[tid] = x[bc * T + t0 + tid];
    __syncthreads();
    const int f = fb * 256 + tid;
    const double om = 2.0 * M_PI / (double)T;
    double s0, c0, sw, cw;
    sincos(om * (double)((f * t0) & (T - 1)), &s0, &c0);
    sincos(om * (double)(f & (T - 1)), &sw, &cw);
    double curR = c0, curI = -s0;          // e^{-i th0}
    const double wR = cw, wI = -sw;        // e^{-i om f}
    double accR = 0.0, accI = 0.0;
    #pragma unroll 4
    for (int t = 0; t < CHLEN; ++t) {
        double v = (double)xs[t];
        accR += v * curR;
        accI += v * curI;
        double nR = curR * wR - curI * wI;
        double nI = curR * wI + curI * wR;
        curR = nR; curI = nI;
    }
    Xp[(size_t)((bc * FMAX + f) * NCH + ch) * 2 + 0] = accR;
    Xp[(size_t)((bc * FMAX + f) * NCH + ch) * 2 + 1] = accI;
}

// Kernel B: per (bc, band) analytic-signal synthesis via oscillator recurrence
// over band bins. Each thread carries its 6 t-values through one bin pass.
__global__ void band_kernel(const double* __restrict__ Xp,
                            unsigned char* __restrict__ idx_buf,
                            float* __restrict__ amp_buf) {
    __shared__ double sXr[160];
    __shared__ double sXi[160];
    const int bc = blockIdx.x;
    const int band = blockIdx.y;
    const int tid = threadIdx.x;
    int fl, fh;
    band_range(band, &fl, &fh);
    const int nb = fh - fl + 1;
    for (int i = tid; i < nb; i += 256) {
        const double* p = Xp + (size_t)((bc * FMAX + fl + i) * NCH) * 2;
        double r = 0.0, im = 0.0;
        #pragma unroll
        for (int c = 0; c < NCH; ++c) { r += p[2 * c]; im += p[2 * c + 1]; }
        sXr[i] = r; sXi[i] = im;
    }
    __syncthreads();

    const double om = 2.0 * M_PI / (double)T;
    double curR[6], curI[6], wR[6], wI[6], accR[6], accI[6];
    #pragma unroll
    for (int j = 0; j < 6; ++j) {
        const int t = tid + j * 256 + EDGE;
        double s, c;
        sincos(om * (double)((fl * t) & (T - 1)), &s, &c);
        curR[j] = c; curI[j] = s;          // e^{+i om fl t}
        sincos(om * (double)(t & (T - 1)), &s, &c);
        wR[j] = c; wI[j] = s;              // e^{+i om t}
        accR[j] = 0.0; accI[j] = 0.0;
    }
    for (int i = 0; i < nb; ++i) {
        const double Xr = sXr[i], Xi = sXi[i];   // broadcast read
        #pragma unroll
        for (int j = 0; j < 6; ++j) {
            accR[j] += Xr * curR[j] - Xi * curI[j];
            accI[j] += Xr * curI[j] + Xi * curR[j];
            double nR = curR[j] * wR[j] - curI[j] * wI[j];
            double nI = curR[j] * wI[j] + curI[j] * wR[j];
            curR[j] = nR; curI[j] = nI;
        }
    }
    #pragma unroll
    for (int j = 0; j < 6; ++j) {
        const int trel = tid + j * 256;
        if (band < PHA_N) {
            double pha = atan2(accI[j], accR[j]);        // (-pi, pi]
            double width = 2.0 * M_PI / (double)NBINS;
            int b = (int)floor((pha + M_PI) / width);
            if (b < 0) b = 0;
            if (b > NBINS - 1) b = NBINS - 1;
            idx_buf[(size_t)(bc * PHA_N + band) * TT + trel] = (unsigned char)b;
        } else {
            double amp = sqrt(accR[j] * accR[j] + accI[j] * accI[j]) * (2.0 / (double)T);
            amp_buf[(size_t)(bc * AMP_N + (band - PHA_N)) * TT + trel] = (float)amp;
        }
    }
}

// Kernel C: per (bc, phase band p): fused counts + per-amp-band bin sums + MI.
// 248 active threads = 31 rows (30 amp bands + 1 count row) x 8 t-groups.
// fp32 partials in LDS (~19 KB) -> ~7 blocks/CU to hide LDS RMW latency.
#define PK 19   // padded bin stride for partials
#define NROW 31 // 30 amp bands + counts row
__global__ void mi_kernel(const unsigned char* __restrict__ idx_buf,
                          const float* __restrict__ amp_buf,
                          float* __restrict__ out) {
    __shared__ float part[NROW * 8 * PK];     // row = tid = a*8+g
    __shared__ float sums[NROW * NBINS];
    const int blk = blockIdx.x;               // bc*50 + p
    const int bc = blk / PHA_N;
    const int p = blk % PHA_N;
    const int tid = threadIdx.x;

    for (int i = tid; i < NROW * 8 * PK; i += 256) part[i] = 0.0f;
    __syncthreads();

    if (tid < NROW * 8) {
        const int a = tid >> 3;     // 0..30 (30 == counts)
        const int g = tid & 7;      // contiguous 192-t chunk per thread
        const unsigned int* sp =
            (const unsigned int*)(idx_buf + (size_t)(bc * PHA_N + p) * TT) + g * 48;
        const float4* ap = (a < AMP_N)
            ? (const float4*)(amp_buf + (size_t)(bc * AMP_N + a) * TT) + g * 48
            : (const float4*)0;
        float* myp = part + tid * PK;
        for (int it = 0; it < 48; ++it) {
            const unsigned int pk = sp[it];
            float4 v;
            if (a < AMP_N) v = ap[it];
            else { v.x = 1.0f; v.y = 1.0f; v.z = 1.0f; v.w = 1.0f; }
            myp[pk & 0xff]         += v.x;
            myp[(pk >> 8) & 0xff]  += v.y;
            myp[(pk >> 16) & 0xff] += v.z;
            myp[(pk >> 24) & 0xff] += v.w;
        }
    }
    __syncthreads();

    for (int i = tid; i < NROW * NBINS; i += 256) {
        const int a = i / NBINS, k = i - a * NBINS;
        float s = 0.0f;
        #pragma unroll
        for (int g = 0; g < 8; ++g) s += part[(a * 8 + g) * PK + k];
        sums[i] = s;
    }
    __syncthreads();

    if (tid < AMP_N) {
        const int a = tid;
        double m[NBINS], tot = 0.0;
        for (int k = 0; k < NBINS; ++k) {
            double cnt = (double)sums[AMP_N * NBINS + k];   // counts row
            double denom = cnt > 1e-9 ? cnt : 1e-9;
            m[k] = (double)sums[a * NBINS + k] / denom;
            tot += m[k];
        }
        double dt = tot > 1e-9 ? tot : 1e-9;
        double acc = 0.0;
        for (int k = 0; k < NBINS; ++k) {
            double pr = m[k] / dt;
            acc += pr * log(pr + 1e-9);
        }
        const double lognb = log((double)NBINS);
        double mi = (lognb + acc) / lognb;
        out[(size_t)(bc * PHA_N + p) * AMP_N + a] = (float)mi;
    }
}

extern "C" void kernel_launch(void* const* d_in, const int* in_sizes, int n_in,
                              void* d_out, int out_size, void* d_ws, size_t ws_size,
                              hipStream_t stream) {
    const float* x = (const float*)d_in[0];
    float* out = (float*)d_out;
    char* ws = (char*)d_ws;
    // workspace layout (all regions fully written before read each call):
    //   idx_buf: 16*50*1536 u8                    = 1,228,800 B
    //   amp_buf: 16*30*1536 f32                   = 2,949,120 B
    //   Xp:      16*768*8 chunks complex double   = 1,572,864 B   (~5.5 MB total)
    unsigned char* idx_buf = (unsigned char*)ws;
    float* amp_buf = (float*)(ws + 1228800);
    double* Xp = (double*)(ws + 1228800 + 2949120);

    dft_kernel<<<dim3(NBC, FMAX / 256, NCH), 256, 0, stream>>>(x, Xp);
    band_kernel<<<dim3(NBC, NBANDS), 256, 0, stream>>>(Xp, idx_buf, amp_buf);
    mi_kernel<<<NBC * PHA_N, 256, 0, stream>>>(idx_buf, amp_buf, out);
}